// Round 1
// baseline (470.650 us; speedup 1.0000x reference)
//
#include <hip/hip_runtime.h>
#include <math.h>

// Problem: M=65536 image rows (D=1024, f32), 8 text vectors (N=4 x n_cls=2),
// Sinkhorn (eps=0.1, max 100 iters, early-exit err<0.01), out = exp(ls)*sim_op[2].
// Design: one fused kernel, thread t owns image row t. sim/K for the 8 text
// vectors live in registers. Grid-wide Sinkhorn reductions via device-scope
// atomics into per-iteration ws slots + a manual grid barrier (256 blocks on
// 256 CUs -> co-resident). 256MB img read once: HBM-bound, ~41us floor.

#define TPB 256
#define NBLK 256
#define NV 8            // (n, c) pairs, v = n*2 + c
#define DV 256          // D=1024 in float4 units
#define SINK_MAX 100
#define SINK_THRESH 0.01f

__device__ __forceinline__ void grid_barrier(unsigned* bar) {
  __syncthreads();
  if (threadIdx.x == 0) {
    __threadfence();
    unsigned target = __hip_atomic_load(&bar[1], __ATOMIC_RELAXED, __HIP_MEMORY_SCOPE_AGENT) + 1u;
    unsigned arrived = __hip_atomic_fetch_add(&bar[0], 1u, __ATOMIC_ACQ_REL, __HIP_MEMORY_SCOPE_AGENT) + 1u;
    if (arrived == gridDim.x) {
      __hip_atomic_store(&bar[0], 0u, __ATOMIC_RELAXED, __HIP_MEMORY_SCOPE_AGENT);
      __hip_atomic_fetch_add(&bar[1], 1u, __ATOMIC_ACQ_REL, __HIP_MEMORY_SCOPE_AGENT);
    } else {
      while (__hip_atomic_load(&bar[1], __ATOMIC_ACQUIRE, __HIP_MEMORY_SCOPE_AGENT) < target) {
        __builtin_amdgcn_s_sleep(2);
      }
    }
    __threadfence();
  }
  __syncthreads();
}

__global__ __launch_bounds__(TPB) void sinkhorn_fused(
    const float* __restrict__ img, const float* __restrict__ txt,
    const float* __restrict__ ls, float* __restrict__ out,
    unsigned* __restrict__ bar, float* __restrict__ slots)
{
  __shared__ float4 stxt[NV * DV];   // 32 KB: all 8 text vectors
  __shared__ float red[4][12];       // per-wave partials

  const int tid = threadIdx.x;
  const int m = blockIdx.x * TPB + tid;

  // stage text features into LDS (coalesced)
  const float4* t4 = reinterpret_cast<const float4*>(txt);
  for (int i = tid; i < NV * DV; i += TPB) stxt[i] = t4[i];
  __syncthreads();

  // ---- phase 1: sim[v] = dot(img[m], txt[v]) , v = n*2 + c ----
  float acc[NV];
  #pragma unroll
  for (int v = 0; v < NV; ++v) acc[v] = 0.f;

  const float4* row = reinterpret_cast<const float4*>(img) + (size_t)m * DV;
  #pragma unroll 4
  for (int j = 0; j < DV; ++j) {
    float4 a = row[j];
    #pragma unroll
    for (int v = 0; v < NV; ++v) {
      float4 t = stxt[v * DV + j];   // broadcast across lanes: conflict-free
      acc[v] += a.x * t.x + a.y * t.y + a.z * t.z + a.w * t.w;
    }
  }

  // K = exp(-(1-sim)/0.1)
  float K[NV];
  #pragma unroll
  for (int v = 0; v < NV; ++v) K[v] = expf(10.f * (acc[v] - 1.f));

  // ---- phase 2: Sinkhorn. batch b = c index (v&1). ----
  float cvec[NV];
  #pragma unroll
  for (int v = 0; v < NV; ++v) cvec[v] = 1.f;   // c0 = ones
  float r_prev[2] = {1.f, 1.f};                  // r0 = ones
  float err = INFINITY;
  int it = 0;

  while (it < SINK_MAX && err >= SINK_THRESH) {
    // body: r = u / (K c);  partials for c = v / (K^T r);  err = mean|r-r0|
    float part[9];
    float errp = 0.f;
    #pragma unroll
    for (int b = 0; b < 2; ++b) {
      float denom = 0.f;
      #pragma unroll
      for (int n = 0; n < 4; ++n) denom += K[n*2+b] * cvec[n*2+b];
      float r = (1.f / 65536.f) / denom;         // u = 1/M
      errp += fabsf(r - r_prev[b]);
      r_prev[b] = r;
      #pragma unroll
      for (int n = 0; n < 4; ++n) part[1 + b*4 + n] = K[n*2+b] * r;
    }
    part[0] = errp;

    // block-reduce 9 scalars, then atomic into this iteration's slot
    #pragma unroll
    for (int k = 0; k < 9; ++k) {
      float s = part[k];
      #pragma unroll
      for (int off = 1; off < 64; off <<= 1) s += __shfl_xor(s, off, 64);
      if ((tid & 63) == 0) red[tid >> 6][k] = s;
    }
    __syncthreads();
    if (tid < 9) {
      float s = red[0][tid] + red[1][tid] + red[2][tid] + red[3][tid];
      atomicAdd(&slots[it * 9 + tid], s);        // device-scope
    }
    grid_barrier(bar);

    // read reduced values (agent-scope loads: coherent across XCDs)
    err = __hip_atomic_load(&slots[it * 9 + 0], __ATOMIC_RELAXED, __HIP_MEMORY_SCOPE_AGENT)
          * (1.f / 131072.f);                    // mean over [2, 65536]
    #pragma unroll
    for (int b = 0; b < 2; ++b) {
      #pragma unroll
      for (int n = 0; n < 4; ++n) {
        float S = __hip_atomic_load(&slots[it * 9 + 1 + b*4 + n],
                                    __ATOMIC_RELAXED, __HIP_MEMORY_SCOPE_AGENT);
        cvec[n*2+b] = 0.25f / S;                 // v = 1/N
      }
    }
    ++it;
  }

  // ---- epilogue: sim_op[b] = sum_{m,n} r_m c_n K sim ----
  float op[2];
  #pragma unroll
  for (int b = 0; b < 2; ++b) {
    float s = 0.f;
    #pragma unroll
    for (int n = 0; n < 4; ++n) s += cvec[n*2+b] * K[n*2+b] * acc[n*2+b];
    op[b] = s * r_prev[b];
  }
  #pragma unroll
  for (int k = 0; k < 2; ++k) {
    float s = op[k];
    #pragma unroll
    for (int off = 1; off < 64; off <<= 1) s += __shfl_xor(s, off, 64);
    if ((tid & 63) == 0) red[tid >> 6][k] = s;
  }
  __syncthreads();
  if (tid < 2) {
    float tot = red[0][tid] + red[1][tid] + red[2][tid] + red[3][tid];
    atomicAdd(&out[tid], expf(ls[0]) * tot);
  }
}

extern "C" void kernel_launch(void* const* d_in, const int* in_sizes, int n_in,
                              void* d_out, int out_size, void* d_ws, size_t ws_size,
                              hipStream_t stream) {
  const float* img = (const float*)d_in[0];
  const float* txt = (const float*)d_in[1];
  const float* ls  = (const float*)d_in[2];
  float* out = (float*)d_out;

  // zero output (we atomicAdd into it) and ws (barrier state + 100 iter slots)
  hipMemsetAsync(d_out, 0, 2 * sizeof(float), stream);
  hipMemsetAsync(d_ws, 0, 4096, stream);

  unsigned* bar = (unsigned*)d_ws;                    // [0]=count, [1]=gen
  float* slots = (float*)((char*)d_ws + 64);          // 100 iters x 9 floats

  sinkhorn_fused<<<NBLK, TPB, 0, stream>>>(img, txt, ls, out, bar, slots);
}

// Round 2
// 442.512 us; speedup vs baseline: 1.0636x; 1.0636x over previous
//
#include <hip/hip_runtime.h>
#include <math.h>

// MGPATH Sinkhorn-OT logits, M=65536, D=1024, 8 text vectors.
// R2 design: two kernels.
//  k1 (sim_kernel): full-occupancy streaming GEMV, 8 threads per image row,
//     writes sim[m][8] (2MB) to ws. No barrier -> saturates HBM.
//  k2 (sinkhorn_kernel): persistent 256-block grid-barrier kernel; loads
//     sim[m][8], Sinkhorn in registers, epilogue atomicAdd to out.
// ws layout: [0,64) barrier, [64,4096) iter slots (100*9 floats), [4096,..) sim8.

#define TPB 256
#define K1_BLOCKS 2048          // 32 rows/block * 2048 = 65536
#define K2_BLOCKS 256
#define NV 8                    // (n, c) pairs, v = n*2 + c
#define DV 256                  // D=1024 in float4 units
#define SINK_MAX 100
#define SINK_THRESH 0.01f

__device__ __forceinline__ void grid_barrier(unsigned* bar) {
  __syncthreads();
  if (threadIdx.x == 0) {
    __threadfence();
    unsigned target = __hip_atomic_load(&bar[1], __ATOMIC_RELAXED, __HIP_MEMORY_SCOPE_AGENT) + 1u;
    unsigned arrived = __hip_atomic_fetch_add(&bar[0], 1u, __ATOMIC_ACQ_REL, __HIP_MEMORY_SCOPE_AGENT) + 1u;
    if (arrived == gridDim.x) {
      __hip_atomic_store(&bar[0], 0u, __ATOMIC_RELAXED, __HIP_MEMORY_SCOPE_AGENT);
      __hip_atomic_fetch_add(&bar[1], 1u, __ATOMIC_ACQ_REL, __HIP_MEMORY_SCOPE_AGENT);
    } else {
      while (__hip_atomic_load(&bar[1], __ATOMIC_ACQUIRE, __HIP_MEMORY_SCOPE_AGENT) < target) {
        __builtin_amdgcn_s_sleep(2);
      }
    }
    __threadfence();
  }
  __syncthreads();
}

// ---------------- kernel 1: sim[m][v] = dot(img[m], txt[v]) ----------------
// 8 threads per row; thread's chunk c = tid&7 covers float4 indices j = c+8*i.
// Lanes 0..7 read 128B contiguous per row; 8 rows per wave.
__global__ __launch_bounds__(TPB) void sim_kernel(
    const float* __restrict__ img, const float* __restrict__ txt,
    float4* __restrict__ simout)
{
  __shared__ float4 stxt[NV * DV];   // 32 KB
  const int tid = threadIdx.x;
  const float4* t4 = reinterpret_cast<const float4*>(txt);
  for (int i = tid; i < NV * DV; i += TPB) stxt[i] = t4[i];
  __syncthreads();

  const int c = tid & 7;
  const int row = blockIdx.x * 32 + (tid >> 3);
  const float4* row4 = reinterpret_cast<const float4*>(img) + (size_t)row * DV;

  float acc[NV];
  #pragma unroll
  for (int v = 0; v < NV; ++v) acc[v] = 0.f;

  for (int i0 = 0; i0 < 32; i0 += 8) {
    float4 a[8];
    #pragma unroll
    for (int t = 0; t < 8; ++t) a[t] = row4[c + 8 * (i0 + t)];   // 8 loads in flight
    #pragma unroll
    for (int t = 0; t < 8; ++t) {
      const int j = c + 8 * (i0 + t);
      #pragma unroll
      for (int v = 0; v < NV; ++v) {
        float4 tt = stxt[v * DV + j];   // 8-lane broadcast groups, conflict-free
        acc[v] += a[t].x * tt.x + a[t].y * tt.y + a[t].z * tt.z + a[t].w * tt.w;
      }
    }
  }

  // reduce the 8 chunk-partials (lanes c=0..7 of each row)
  #pragma unroll
  for (int v = 0; v < NV; ++v) {
    float s = acc[v];
    s += __shfl_xor(s, 1, 64);
    s += __shfl_xor(s, 2, 64);
    s += __shfl_xor(s, 4, 64);
    acc[v] = s;
  }
  if (c == 0) {
    simout[(size_t)row * 2]     = make_float4(acc[0], acc[1], acc[2], acc[3]);
    simout[(size_t)row * 2 + 1] = make_float4(acc[4], acc[5], acc[6], acc[7]);
  }
}

// ---------------- kernel 2: Sinkhorn + epilogue (persistent, barrier) -------
__global__ __launch_bounds__(TPB) void sinkhorn_kernel(
    const float4* __restrict__ simout, const float* __restrict__ ls,
    float* __restrict__ out, unsigned* __restrict__ bar,
    float* __restrict__ slots)
{
  __shared__ float red[4][12];
  const int tid = threadIdx.x;
  const int m = blockIdx.x * TPB + tid;

  float4 s0 = simout[(size_t)m * 2];
  float4 s1 = simout[(size_t)m * 2 + 1];
  const float sim[NV] = {s0.x, s0.y, s0.z, s0.w, s1.x, s1.y, s1.z, s1.w};

  float K[NV];
  #pragma unroll
  for (int v = 0; v < NV; ++v) K[v] = expf(10.f * (sim[v] - 1.f));

  float cvec[NV];
  #pragma unroll
  for (int v = 0; v < NV; ++v) cvec[v] = 1.f;
  float r_prev[2] = {1.f, 1.f};
  float err = INFINITY;
  int it = 0;

  while (it < SINK_MAX && err >= SINK_THRESH) {
    float part[9];
    float errp = 0.f;
    #pragma unroll
    for (int b = 0; b < 2; ++b) {
      float denom = 0.f;
      #pragma unroll
      for (int n = 0; n < 4; ++n) denom += K[n*2+b] * cvec[n*2+b];
      float r = (1.f / 65536.f) / denom;
      errp += fabsf(r - r_prev[b]);
      r_prev[b] = r;
      #pragma unroll
      for (int n = 0; n < 4; ++n) part[1 + b*4 + n] = K[n*2+b] * r;
    }
    part[0] = errp;

    #pragma unroll
    for (int k = 0; k < 9; ++k) {
      float s = part[k];
      #pragma unroll
      for (int off = 1; off < 64; off <<= 1) s += __shfl_xor(s, off, 64);
      if ((tid & 63) == 0) red[tid >> 6][k] = s;
    }
    __syncthreads();
    if (tid < 9) {
      float s = red[0][tid] + red[1][tid] + red[2][tid] + red[3][tid];
      atomicAdd(&slots[it * 9 + tid], s);
    }
    grid_barrier(bar);

    err = __hip_atomic_load(&slots[it * 9 + 0], __ATOMIC_RELAXED, __HIP_MEMORY_SCOPE_AGENT)
          * (1.f / 131072.f);
    #pragma unroll
    for (int b = 0; b < 2; ++b) {
      #pragma unroll
      for (int n = 0; n < 4; ++n) {
        float S = __hip_atomic_load(&slots[it * 9 + 1 + b*4 + n],
                                    __ATOMIC_RELAXED, __HIP_MEMORY_SCOPE_AGENT);
        cvec[n*2+b] = 0.25f / S;
      }
    }
    ++it;
  }

  float op[2];
  #pragma unroll
  for (int b = 0; b < 2; ++b) {
    float s = 0.f;
    #pragma unroll
    for (int n = 0; n < 4; ++n) s += cvec[n*2+b] * K[n*2+b] * sim[n*2+b];
    op[b] = s * r_prev[b];
  }
  #pragma unroll
  for (int k = 0; k < 2; ++k) {
    float s = op[k];
    #pragma unroll
    for (int off = 1; off < 64; off <<= 1) s += __shfl_xor(s, off, 64);
    if ((tid & 63) == 0) red[tid >> 6][k] = s;
  }
  __syncthreads();
  if (tid < 2) {
    float tot = red[0][tid] + red[1][tid] + red[2][tid] + red[3][tid];
    atomicAdd(&out[tid], expf(ls[0]) * tot);
  }
}

// ---------------- fallback: proven single fused kernel (R1) ----------------
__global__ __launch_bounds__(TPB) void sinkhorn_fused(
    const float* __restrict__ img, const float* __restrict__ txt,
    const float* __restrict__ ls, float* __restrict__ out,
    unsigned* __restrict__ bar, float* __restrict__ slots)
{
  __shared__ float4 stxt[NV * DV];
  __shared__ float red[4][12];
  const int tid = threadIdx.x;
  const int m = blockIdx.x * TPB + tid;

  const float4* t4 = reinterpret_cast<const float4*>(txt);
  for (int i = tid; i < NV * DV; i += TPB) stxt[i] = t4[i];
  __syncthreads();

  float acc[NV];
  #pragma unroll
  for (int v = 0; v < NV; ++v) acc[v] = 0.f;
  const float4* row = reinterpret_cast<const float4*>(img) + (size_t)m * DV;
  #pragma unroll 4
  for (int j = 0; j < DV; ++j) {
    float4 a = row[j];
    #pragma unroll
    for (int v = 0; v < NV; ++v) {
      float4 t = stxt[v * DV + j];
      acc[v] += a.x * t.x + a.y * t.y + a.z * t.z + a.w * t.w;
    }
  }
  float K[NV];
  #pragma unroll
  for (int v = 0; v < NV; ++v) K[v] = expf(10.f * (acc[v] - 1.f));
  float cvec[NV];
  #pragma unroll
  for (int v = 0; v < NV; ++v) cvec[v] = 1.f;
  float r_prev[2] = {1.f, 1.f};
  float err = INFINITY;
  int it = 0;
  while (it < SINK_MAX && err >= SINK_THRESH) {
    float part[9];
    float errp = 0.f;
    #pragma unroll
    for (int b = 0; b < 2; ++b) {
      float denom = 0.f;
      #pragma unroll
      for (int n = 0; n < 4; ++n) denom += K[n*2+b] * cvec[n*2+b];
      float r = (1.f / 65536.f) / denom;
      errp += fabsf(r - r_prev[b]);
      r_prev[b] = r;
      #pragma unroll
      for (int n = 0; n < 4; ++n) part[1 + b*4 + n] = K[n*2+b] * r;
    }
    part[0] = errp;
    #pragma unroll
    for (int k = 0; k < 9; ++k) {
      float s = part[k];
      #pragma unroll
      for (int off = 1; off < 64; off <<= 1) s += __shfl_xor(s, off, 64);
      if ((tid & 63) == 0) red[tid >> 6][k] = s;
    }
    __syncthreads();
    if (tid < 9) {
      float s = red[0][tid] + red[1][tid] + red[2][tid] + red[3][tid];
      atomicAdd(&slots[it * 9 + tid], s);
    }
    grid_barrier(bar);
    err = __hip_atomic_load(&slots[it * 9 + 0], __ATOMIC_RELAXED, __HIP_MEMORY_SCOPE_AGENT)
          * (1.f / 131072.f);
    #pragma unroll
    for (int b = 0; b < 2; ++b) {
      #pragma unroll
      for (int n = 0; n < 4; ++n) {
        float S = __hip_atomic_load(&slots[it * 9 + 1 + b*4 + n],
                                    __ATOMIC_RELAXED, __HIP_MEMORY_SCOPE_AGENT);
        cvec[n*2+b] = 0.25f / S;
      }
    }
    ++it;
  }
  float op[2];
  #pragma unroll
  for (int b = 0; b < 2; ++b) {
    float s = 0.f;
    #pragma unroll
    for (int n = 0; n < 4; ++n) s += cvec[n*2+b] * K[n*2+b] * acc[n*2+b];
    op[b] = s * r_prev[b];
  }
  #pragma unroll
  for (int k = 0; k < 2; ++k) {
    float s = op[k];
    #pragma unroll
    for (int off = 1; off < 64; off <<= 1) s += __shfl_xor(s, off, 64);
    if ((tid & 63) == 0) red[tid >> 6][k] = s;
  }
  __syncthreads();
  if (tid < 2) {
    float tot = red[0][tid] + red[1][tid] + red[2][tid] + red[3][tid];
    atomicAdd(&out[tid], expf(ls[0]) * tot);
  }
}

extern "C" void kernel_launch(void* const* d_in, const int* in_sizes, int n_in,
                              void* d_out, int out_size, void* d_ws, size_t ws_size,
                              hipStream_t stream) {
  const float* img = (const float*)d_in[0];
  const float* txt = (const float*)d_in[1];
  const float* ls  = (const float*)d_in[2];
  float* out = (float*)d_out;

  hipMemsetAsync(d_out, 0, 2 * sizeof(float), stream);
  hipMemsetAsync(d_ws, 0, 4096, stream);   // barrier + iter slots

  unsigned* bar = (unsigned*)d_ws;
  float* slots = (float*)((char*)d_ws + 64);
  float4* sim8 = (float4*)((char*)d_ws + 4096);

  const size_t need = 4096 + (size_t)65536 * 8 * sizeof(float);
  if (ws_size >= need) {
    sim_kernel<<<K1_BLOCKS, TPB, 0, stream>>>(img, txt, sim8);
    sinkhorn_kernel<<<K2_BLOCKS, TPB, 0, stream>>>(sim8, ls, out, bar, slots);
  } else {
    sinkhorn_fused<<<K2_BLOCKS, TPB, 0, stream>>>(img, txt, ls, out, bar, slots);
  }
}

// Round 4
// 399.856 us; speedup vs baseline: 1.1771x; 1.1067x over previous
//
#include <hip/hip_runtime.h>
#include <math.h>

// MGPATH Sinkhorn-OT logits, M=65536, D=1024, 8 text vectors.
// R3 (resubmit after broker timeout): two kernels.
//  k1 (sim_kernel): full-occupancy streaming GEMV, 8 threads/row, writes
//     sim[m][8] (2MB) to ws. ~50us (HBM floor 41us).
//  k2 (sinkhorn_kernel): persistent 64-block x 1024-thread grid-barrier
//     kernel (4 waves/SIMD, cheap 64-arrival barrier, 64-way atomics).
// ws layout: [0,64) barrier, [64,4096) iter slots (100*9 floats), [4096,..) sim8.
// dur_us includes ~350us of harness re-poison/restore we cannot control.

#define TPB 256
#define K1_BLOCKS 2048          // 32 rows/block * 2048 = 65536
#define TPB2 1024
#define K2_BLOCKS 64            // 64 * 1024 = 65536 threads, 1 row each
#define NV 8                    // (n, c) pairs, v = n*2 + c
#define DV 256                  // D=1024 in float4 units
#define SINK_MAX 100
#define SINK_THRESH 0.01f

__device__ __forceinline__ void grid_barrier(unsigned* bar, unsigned nblk) {
  __syncthreads();
  if (threadIdx.x == 0) {
    __threadfence();
    unsigned target = __hip_atomic_load(&bar[1], __ATOMIC_RELAXED, __HIP_MEMORY_SCOPE_AGENT) + 1u;
    unsigned arrived = __hip_atomic_fetch_add(&bar[0], 1u, __ATOMIC_ACQ_REL, __HIP_MEMORY_SCOPE_AGENT) + 1u;
    if (arrived == nblk) {
      __hip_atomic_store(&bar[0], 0u, __ATOMIC_RELAXED, __HIP_MEMORY_SCOPE_AGENT);
      __hip_atomic_fetch_add(&bar[1], 1u, __ATOMIC_ACQ_REL, __HIP_MEMORY_SCOPE_AGENT);
    } else {
      while (__hip_atomic_load(&bar[1], __ATOMIC_ACQUIRE, __HIP_MEMORY_SCOPE_AGENT) < target) {
        __builtin_amdgcn_s_sleep(2);
      }
    }
    __threadfence();
  }
  __syncthreads();
}

// ---------------- kernel 1: sim[m][v] = dot(img[m], txt[v]) ----------------
// 8 threads per row; thread's chunk c = tid&7 covers float4 indices j = c+8*i.
__global__ __launch_bounds__(TPB) void sim_kernel(
    const float* __restrict__ img, const float* __restrict__ txt,
    float4* __restrict__ simout)
{
  __shared__ float4 stxt[NV * DV];   // exactly 32 KB -> 5 blocks/CU
  const int tid = threadIdx.x;
  const float4* t4 = reinterpret_cast<const float4*>(txt);
  for (int i = tid; i < NV * DV; i += TPB) stxt[i] = t4[i];
  __syncthreads();

  const int c = tid & 7;
  const int row = blockIdx.x * 32 + (tid >> 3);
  const float4* row4 = reinterpret_cast<const float4*>(img) + (size_t)row * DV;

  float acc[NV];
  #pragma unroll
  for (int v = 0; v < NV; ++v) acc[v] = 0.f;

  for (int i0 = 0; i0 < 32; i0 += 8) {
    float4 a[8];
    #pragma unroll
    for (int t = 0; t < 8; ++t) a[t] = row4[c + 8 * (i0 + t)];   // 8 loads in flight
    #pragma unroll
    for (int t = 0; t < 8; ++t) {
      const int j = c + 8 * (i0 + t);
      #pragma unroll
      for (int v = 0; v < NV; ++v) {
        float4 tt = stxt[v * DV + j];   // 8-lane broadcast groups, conflict-free
        acc[v] += a[t].x * tt.x + a[t].y * tt.y + a[t].z * tt.z + a[t].w * tt.w;
      }
    }
  }

  #pragma unroll
  for (int v = 0; v < NV; ++v) {
    float s = acc[v];
    s += __shfl_xor(s, 1, 64);
    s += __shfl_xor(s, 2, 64);
    s += __shfl_xor(s, 4, 64);
    acc[v] = s;
  }
  if (c == 0) {
    simout[(size_t)row * 2]     = make_float4(acc[0], acc[1], acc[2], acc[3]);
    simout[(size_t)row * 2 + 1] = make_float4(acc[4], acc[5], acc[6], acc[7]);
  }
}

// ---------------- kernel 2: Sinkhorn + epilogue (persistent, barrier) -------
__global__ __launch_bounds__(TPB2) void sinkhorn_kernel(
    const float4* __restrict__ simout, const float* __restrict__ ls,
    float* __restrict__ out, unsigned* __restrict__ bar,
    float* __restrict__ slots)
{
  __shared__ float red[TPB2 / 64][12];
  const int tid = threadIdx.x;
  const int m = blockIdx.x * TPB2 + tid;

  float4 s0 = simout[(size_t)m * 2];
  float4 s1 = simout[(size_t)m * 2 + 1];
  const float sim[NV] = {s0.x, s0.y, s0.z, s0.w, s1.x, s1.y, s1.z, s1.w};

  float K[NV];
  #pragma unroll
  for (int v = 0; v < NV; ++v) K[v] = expf(10.f * (sim[v] - 1.f));

  float cvec[NV];
  #pragma unroll
  for (int v = 0; v < NV; ++v) cvec[v] = 1.f;
  float r_prev[2] = {1.f, 1.f};
  float err = INFINITY;
  int it = 0;

  while (it < SINK_MAX && err >= SINK_THRESH) {
    float part[9];
    float errp = 0.f;
    #pragma unroll
    for (int b = 0; b < 2; ++b) {
      float denom = 0.f;
      #pragma unroll
      for (int n = 0; n < 4; ++n) denom += K[n*2+b] * cvec[n*2+b];
      float r = (1.f / 65536.f) / denom;         // u = 1/M
      errp += fabsf(r - r_prev[b]);
      r_prev[b] = r;
      #pragma unroll
      for (int n = 0; n < 4; ++n) part[1 + b*4 + n] = K[n*2+b] * r;
    }
    part[0] = errp;

    #pragma unroll
    for (int k = 0; k < 9; ++k) {
      float s = part[k];
      #pragma unroll
      for (int off = 1; off < 64; off <<= 1) s += __shfl_xor(s, off, 64);
      if ((tid & 63) == 0) red[tid >> 6][k] = s;
    }
    __syncthreads();
    if (tid < 9) {
      float s = 0.f;
      #pragma unroll
      for (int w = 0; w < TPB2 / 64; ++w) s += red[w][tid];
      atomicAdd(&slots[it * 9 + tid], s);        // 64 adds per address
    }
    grid_barrier(bar, K2_BLOCKS);

    err = __hip_atomic_load(&slots[it * 9 + 0], __ATOMIC_RELAXED, __HIP_MEMORY_SCOPE_AGENT)
          * (1.f / 131072.f);                    // mean over [2, 65536]
    #pragma unroll
    for (int b = 0; b < 2; ++b) {
      #pragma unroll
      for (int n = 0; n < 4; ++n) {
        float S = __hip_atomic_load(&slots[it * 9 + 1 + b*4 + n],
                                    __ATOMIC_RELAXED, __HIP_MEMORY_SCOPE_AGENT);
        cvec[n*2+b] = 0.25f / S;                 // v = 1/N
      }
    }
    ++it;
  }

  float op[2];
  #pragma unroll
  for (int b = 0; b < 2; ++b) {
    float s = 0.f;
    #pragma unroll
    for (int n = 0; n < 4; ++n) s += cvec[n*2+b] * K[n*2+b] * sim[n*2+b];
    op[b] = s * r_prev[b];
  }
  #pragma unroll
  for (int k = 0; k < 2; ++k) {
    float s = op[k];
    #pragma unroll
    for (int off = 1; off < 64; off <<= 1) s += __shfl_xor(s, off, 64);
    if ((tid & 63) == 0) red[tid >> 6][k] = s;
  }
  __syncthreads();
  if (tid < 2) {
    float s = 0.f;
    #pragma unroll
    for (int w = 0; w < TPB2 / 64; ++w) s += red[w][tid];
    atomicAdd(&out[tid], expf(ls[0]) * s);
  }
}

// ---------------- fallback: proven single fused kernel (R1) ----------------
__global__ __launch_bounds__(TPB) void sinkhorn_fused(
    const float* __restrict__ img, const float* __restrict__ txt,
    const float* __restrict__ ls, float* __restrict__ out,
    unsigned* __restrict__ bar, float* __restrict__ slots)
{
  __shared__ float4 stxt[NV * DV];
  __shared__ float red[4][12];
  const int tid = threadIdx.x;
  const int m = blockIdx.x * TPB + tid;

  const float4* t4 = reinterpret_cast<const float4*>(txt);
  for (int i = tid; i < NV * DV; i += TPB) stxt[i] = t4[i];
  __syncthreads();

  float acc[NV];
  #pragma unroll
  for (int v = 0; v < NV; ++v) acc[v] = 0.f;
  const float4* row = reinterpret_cast<const float4*>(img) + (size_t)m * DV;
  #pragma unroll 4
  for (int j = 0; j < DV; ++j) {
    float4 a = row[j];
    #pragma unroll
    for (int v = 0; v < NV; ++v) {
      float4 t = stxt[v * DV + j];
      acc[v] += a.x * t.x + a.y * t.y + a.z * t.z + a.w * t.w;
    }
  }
  float K[NV];
  #pragma unroll
  for (int v = 0; v < NV; ++v) K[v] = expf(10.f * (acc[v] - 1.f));
  float cvec[NV];
  #pragma unroll
  for (int v = 0; v < NV; ++v) cvec[v] = 1.f;
  float r_prev[2] = {1.f, 1.f};
  float err = INFINITY;
  int it = 0;
  while (it < SINK_MAX && err >= SINK_THRESH) {
    float part[9];
    float errp = 0.f;
    #pragma unroll
    for (int b = 0; b < 2; ++b) {
      float denom = 0.f;
      #pragma unroll
      for (int n = 0; n < 4; ++n) denom += K[n*2+b] * cvec[n*2+b];
      float r = (1.f / 65536.f) / denom;
      errp += fabsf(r - r_prev[b]);
      r_prev[b] = r;
      #pragma unroll
      for (int n = 0; n < 4; ++n) part[1 + b*4 + n] = K[n*2+b] * r;
    }
    part[0] = errp;
    #pragma unroll
    for (int k = 0; k < 9; ++k) {
      float s = part[k];
      #pragma unroll
      for (int off = 1; off < 64; off <<= 1) s += __shfl_xor(s, off, 64);
      if ((tid & 63) == 0) red[tid >> 6][k] = s;
    }
    __syncthreads();
    if (tid < 9) {
      float s = red[0][tid] + red[1][tid] + red[2][tid] + red[3][tid];
      atomicAdd(&slots[it * 9 + tid], s);
    }
    grid_barrier(bar, 256);
    err = __hip_atomic_load(&slots[it * 9 + 0], __ATOMIC_RELAXED, __HIP_MEMORY_SCOPE_AGENT)
          * (1.f / 131072.f);
    #pragma unroll
    for (int b = 0; b < 2; ++b) {
      #pragma unroll
      for (int n = 0; n < 4; ++n) {
        float S = __hip_atomic_load(&slots[it * 9 + 1 + b*4 + n],
                                    __ATOMIC_RELAXED, __HIP_MEMORY_SCOPE_AGENT);
        cvec[n*2+b] = 0.25f / S;
      }
    }
    ++it;
  }
  float op[2];
  #pragma unroll
  for (int b = 0; b < 2; ++b) {
    float s = 0.f;
    #pragma unroll
    for (int n = 0; n < 4; ++n) s += cvec[n*2+b] * K[n*2+b] * acc[n*2+b];
    op[b] = s * r_prev[b];
  }
  #pragma unroll
  for (int k = 0; k < 2; ++k) {
    float s = op[k];
    #pragma unroll
    for (int off = 1; off < 64; off <<= 1) s += __shfl_xor(s, off, 64);
    if ((tid & 63) == 0) red[tid >> 6][k] = s;
  }
  __syncthreads();
  if (tid < 2) {
    float tot = red[0][tid] + red[1][tid] + red[2][tid] + red[3][tid];
    atomicAdd(&out[tid], expf(ls[0]) * tot);
  }
}

extern "C" void kernel_launch(void* const* d_in, const int* in_sizes, int n_in,
                              void* d_out, int out_size, void* d_ws, size_t ws_size,
                              hipStream_t stream) {
  const float* img = (const float*)d_in[0];
  const float* txt = (const float*)d_in[1];
  const float* ls  = (const float*)d_in[2];
  float* out = (float*)d_out;

  hipMemsetAsync(d_out, 0, 2 * sizeof(float), stream);
  hipMemsetAsync(d_ws, 0, 4096, stream);   // barrier + iter slots

  unsigned* bar = (unsigned*)d_ws;
  float* slots = (float*)((char*)d_ws + 64);
  float4* sim8 = (float4*)((char*)d_ws + 4096);

  const size_t need = 4096 + (size_t)65536 * 8 * sizeof(float);
  if (ws_size >= need) {
    sim_kernel<<<K1_BLOCKS, TPB, 0, stream>>>(img, txt, sim8);
    sinkhorn_kernel<<<K2_BLOCKS, TPB2, 0, stream>>>(sim8, ls, out, bar, slots);
  } else {
    sinkhorn_fused<<<256, TPB, 0, stream>>>(img, txt, ls, out, bar, slots);
  }
}